// Round 4
// baseline (198.080 us; speedup 1.0000x reference)
//
#include <hip/hip_runtime.h>

// ---------------------------------------------------------------------------
// HSTU encoder layer, MI355X.  S=2048 B=2 E=1024 H=16 D=64, M = S*B = 4096.
// cvt(W->bf16) -> LN -> GEMM(in_proj,silu) -> attn(QK^T,silu-mask,PV,*u)
//   -> GEMM 128x64 (out_proj,+src)
// All matmuls: v_mfma_f32_16x16x32_bf16, f32 accum.
// ---------------------------------------------------------------------------

typedef __attribute__((ext_vector_type(8))) short  short8;   // 8 bf16 = 4 VGPR
typedef __attribute__((ext_vector_type(4))) float  floatx4;  // MFMA C/D frag
typedef __attribute__((ext_vector_type(4))) float  fvec4;
typedef __attribute__((ext_vector_type(4))) unsigned short usvec4;
typedef __attribute__((ext_vector_type(4))) int    intx4;

__device__ __forceinline__ unsigned short f2b(float f) {  // f32 -> bf16 RNE
  unsigned u = __builtin_bit_cast(unsigned, f);
  u += 0x7FFFu + ((u >> 16) & 1u);
  return (unsigned short)(u >> 16);
}
__device__ __forceinline__ float b2f(unsigned short h) {
  unsigned u = ((unsigned)h) << 16;
  return __builtin_bit_cast(float, u);
}
// silu via raw v_exp/v_rcp: x<<0 -> exp2(+inf)->rcp->0 OK; x>>0 -> 1*x OK.
__device__ __forceinline__ float silu_f(float x) {
  float e = __builtin_amdgcn_exp2f(-1.44269504f * x);
  return x * __builtin_amdgcn_rcpf(1.f + e);
}
__device__ __forceinline__ void async_copy16(void* lds, const void* g) {
  __builtin_amdgcn_global_load_lds(
      (__attribute__((address_space(1))) void*)(g),
      (__attribute__((address_space(3))) void*)(lds), 16, 0, 0);
}

// ---------------------------------------------------------------- cvt f32->bf16
__global__ void cvt_bf16(const float* __restrict__ s, unsigned short* __restrict__ d, int n4) {
  int i = blockIdx.x * 256 + threadIdx.x;
  if (i < n4) {
    fvec4 v = ((const fvec4*)s)[i];
    usvec4 o = { f2b(v.x), f2b(v.y), f2b(v.z), f2b(v.w) };
    ((usvec4*)d)[i] = o;
  }
}

// ---------------------------------------------------------------- LayerNorm
__global__ __launch_bounds__(256) void ln_kernel(
    const float* __restrict__ x, const float* __restrict__ g,
    const float* __restrict__ b, unsigned short* __restrict__ xn) {
  const int row = blockIdx.x, t = threadIdx.x;
  const float* xr = x + (long)row * 1024;
  fvec4 v = ((const fvec4*)xr)[t];
  float s  = v.x + v.y + v.z + v.w;
  float s2 = v.x*v.x + v.y*v.y + v.z*v.z + v.w*v.w;
  #pragma unroll
  for (int off = 32; off; off >>= 1) { s += __shfl_down(s, off); s2 += __shfl_down(s2, off); }
  __shared__ float red[8];
  int lane = t & 63, w = t >> 6;
  if (lane == 0) { red[w] = s; red[4 + w] = s2; }
  __syncthreads();
  s  = red[0] + red[1] + red[2] + red[3];
  s2 = red[4] + red[5] + red[6] + red[7];
  float mu  = s * (1.f / 1024.f);
  float var = s2 * (1.f / 1024.f) - mu * mu;
  float rs  = rsqrtf(var + 1e-5f);
  fvec4 gg = ((const fvec4*)g)[t];
  fvec4 bb = ((const fvec4*)b)[t];
  usvec4 o = { f2b((v.x - mu) * rs * gg.x + bb.x),
               f2b((v.y - mu) * rs * gg.y + bb.y),
               f2b((v.z - mu) * rs * gg.z + bb.z),
               f2b((v.w - mu) * rs * gg.w + bb.w) };
  ((usvec4*)(xn + (long)row * 1024))[t] = o;
}

// ---------------------------------------------------------------- GEMM in_proj
// C = A * Bw^T, 128x128 tile.  A:(4096,1024) Bw:(2048,1024) bf16.
// epilogue: v=silu(v+bias); n<1024 -> qkv else u (both [m][1024] bf16)
__global__ __launch_bounds__(256, 2) void gemm_in(
    const unsigned short* __restrict__ A, const unsigned short* __restrict__ Bw,
    const float* __restrict__ bias,
    unsigned short* __restrict__ out0, unsigned short* __restrict__ out1) {
  __shared__ __align__(16) unsigned short sA[128 * 32];
  __shared__ __align__(16) unsigned short sB[128 * 32];
  const int t = threadIdx.x;
  const int lane = t & 63, l15 = lane & 15, quad = lane >> 4;
  const int w = t >> 6, wm = w >> 1, wn = w & 1;
  const int m0 = blockIdx.y * 128, n0 = blockIdx.x * 128;
  const int K = 1024;

  floatx4 acc[4][4];
  const floatx4 z4 = {0.f, 0.f, 0.f, 0.f};
  #pragma unroll
  for (int i = 0; i < 4; i++)
    #pragma unroll
    for (int j = 0; j < 4; j++) acc[i][j] = z4;

  for (int kt = 0; kt < 32; ++kt) {
    const int k0 = kt << 5;
    __syncthreads();
    #pragma unroll
    for (int c = 0; c < 2; ++c) {
      int slot = c * 256 + t;
      int row = slot >> 2, col = (slot & 3) << 3;
      async_copy16(&sA[slot * 8], &A[(m0 + row) * K + k0 + col]);
      async_copy16(&sB[slot * 8], &Bw[(n0 + row) * K + k0 + col]);
    }
    __syncthreads();
    short8 af[4], bf[4];
    #pragma unroll
    for (int mr = 0; mr < 4; mr++)
      af[mr] = *(const short8*)&sA[(wm * 64 + mr * 16 + l15) * 32 + quad * 8];
    #pragma unroll
    for (int nr = 0; nr < 4; nr++)
      bf[nr] = *(const short8*)&sB[(wn * 64 + nr * 16 + l15) * 32 + quad * 8];
    #pragma unroll
    for (int mr = 0; mr < 4; mr++)
      #pragma unroll
      for (int nr = 0; nr < 4; nr++)
        acc[mr][nr] = __builtin_amdgcn_mfma_f32_16x16x32_bf16(af[mr], bf[nr], acc[mr][nr], 0, 0, 0);
  }

  #pragma unroll
  for (int mr = 0; mr < 4; mr++) {
    int gm0 = m0 + wm * 64 + mr * 16 + quad * 4;
    #pragma unroll
    for (int nr = 0; nr < 4; nr++) {
      int gn = n0 + wn * 64 + nr * 16 + l15;
      float bv = bias[gn];
      unsigned short* dst = (gn < 1024) ? (out0 + gn) : (out1 + gn - 1024);
      #pragma unroll
      for (int r = 0; r < 4; r++) {
        float v = acc[mr][nr][r] + bv;
        dst[(long)(gm0 + r) * 1024] = f2b(silu_f(v));
      }
    }
  }
}

// ---------------------------------------------------------------- GEMM out_proj
// 128x64 tile (grid 512 -> 2 blocks/CU).
// outf[m][n] = acc + bias[n] + src[m][n]  (f32), N=K=1024.
__global__ __launch_bounds__(256, 2) void gemm_out(
    const unsigned short* __restrict__ A, const unsigned short* __restrict__ Bw,
    const float* __restrict__ bias, const float* __restrict__ src,
    float* __restrict__ outf) {
  __shared__ __align__(16) unsigned short sA[128 * 32];
  __shared__ __align__(16) unsigned short sB[64 * 32];
  const int t = threadIdx.x;
  const int lane = t & 63, l15 = lane & 15, quad = lane >> 4;
  const int w = t >> 6;
  const int m0 = blockIdx.y * 128, n0 = blockIdx.x * 64;

  floatx4 acc[2][4];
  const floatx4 z4 = {0.f, 0.f, 0.f, 0.f};
  #pragma unroll
  for (int i = 0; i < 2; i++)
    #pragma unroll
    for (int j = 0; j < 4; j++) acc[i][j] = z4;

  for (int kt = 0; kt < 32; ++kt) {
    const int k0 = kt << 5;
    __syncthreads();
    #pragma unroll
    for (int c = 0; c < 2; ++c) {
      int slot = c * 256 + t;
      int row = slot >> 2, col = (slot & 3) << 3;
      async_copy16(&sA[slot * 8], &A[(m0 + row) * 1024 + k0 + col]);
    }
    { int row = t >> 2, col = (t & 3) << 3;
      async_copy16(&sB[t * 8], &Bw[(n0 + row) * 1024 + k0 + col]); }
    __syncthreads();
    short8 af[2], bf[4];
    #pragma unroll
    for (int mr = 0; mr < 2; mr++)
      af[mr] = *(const short8*)&sA[(w * 32 + mr * 16 + l15) * 32 + quad * 8];
    #pragma unroll
    for (int nr = 0; nr < 4; nr++)
      bf[nr] = *(const short8*)&sB[(nr * 16 + l15) * 32 + quad * 8];
    #pragma unroll
    for (int mr = 0; mr < 2; mr++)
      #pragma unroll
      for (int nr = 0; nr < 4; nr++)
        acc[mr][nr] = __builtin_amdgcn_mfma_f32_16x16x32_bf16(af[mr], bf[nr], acc[mr][nr], 0, 0, 0);
  }

  #pragma unroll
  for (int mr = 0; mr < 2; mr++) {
    int gm0 = m0 + w * 32 + mr * 16 + quad * 4;
    #pragma unroll
    for (int nr = 0; nr < 4; nr++) {
      int gn = n0 + nr * 16 + l15;
      float bv = bias[gn];
      #pragma unroll
      for (int r = 0; r < 4; r++) {
        long idx = (long)(gm0 + r) * 1024 + gn;
        outf[idx] = acc[mr][nr][r] + bv + src[idx];
      }
    }
  }
}

// ---------------------------------------------------------------- attention
// One block = one (b,h) head x one 64-row q-tile; k-tile = 128; grid 1024.
// Pipeline: kv regs for tile kt+1 are prefetched during tile kt's compute.
// Epilogue: O -> LDS (f32) -> full-128B-line coalesced gated stores.
#define SKS 72    // sK row stride (ushorts) - conflict-free reads/writes
#define SVS 136   // sVt row stride
#define SPS 136   // sP  row stride
#define SOS 68    // sO  row stride (f32)
__global__ __launch_bounds__(256, 4) void attn_kernel(
    const unsigned short* __restrict__ qkv, const unsigned short* __restrict__ u,
    unsigned short* __restrict__ gated) {
  __shared__ __align__(16) unsigned char smem[128 * SKS * 2 + 64 * SVS * 2];  // 35840 B
  unsigned short* sK  = (unsigned short*)smem;                   // [128][72]
  unsigned short* sP  = (unsigned short*)smem;                   // [64][136] (overlaps sK)
  unsigned short* sVt = (unsigned short*)(smem + 128 * SKS * 2); // [64][136] swizzled
  float*          sO  = (float*)smem;                            // [64][68] f32 (epilogue)

  const int t = threadIdx.x, lane = t & 63, l15 = lane & 15, quad = lane >> 4;
  const int w = t >> 6;
  // balanced qi permutation: co-resident sets {g,g+8,g+16,g+24} -> ~equal work
  const int gg = blockIdx.x >> 5, sub = gg >> 3, g = gg & 7;
  const int qi = (sub == 0) ? g : (sub == 1) ? (31 - g) : (sub == 2) ? (g + 8) : (23 - g);
  const int bh = blockIdx.x & 31;
  const int b = bh >> 4, h = bh & 15;
  const long base = (long)b * 1024 + h * 64;   // + s*2048
  const int q0 = qi * 64;
  const int rg = t >> 3, dg = t & 7;           // staging: rows rg*4..+4, cols dg*8..+8
  const int swz0 = (rg >> 1) + dg;             // write-side swizzle base

  // ---- stage Q (64 rows) via sK, pull A-frags to registers ----
  #pragma unroll
  for (int c = 0; c < 2; ++c) {
    int slot = c * 256 + t, row = slot >> 3, cg = slot & 7;
    *(short8*)&sK[row * SKS + cg * 8] =
        *(const short8*)&qkv[base + (long)(q0 + row) * 2048 + cg * 8];
  }
  __syncthreads();
  short8 qf[4][2];
  #pragma unroll
  for (int mr = 0; mr < 4; mr++)
    #pragma unroll
    for (int ks = 0; ks < 2; ks++)
      qf[mr][ks] = *(const short8*)&sK[(mr * 16 + l15) * SKS + ks * 32 + quad * 8];

  floatx4 oacc[4];
  const floatx4 z4 = {0.f, 0.f, 0.f, 0.f};
  #pragma unroll
  for (int i = 0; i < 4; i++) oacc[i] = z4;

  const int d_rd = w * 16 + l15;                       // PV read: this lane's d column
  const int rsw0 = quad + (d_rd & 7) + (d_rd >> 3);    // read-side swizzle base

  const int nkt = (qi >> 1) + 1;
  // ---- prefetch tile 0 ----
  short8 kv[4];
  #pragma unroll
  for (int i = 0; i < 4; ++i)
    kv[i] = *(const short8*)&qkv[base + (long)(rg * 4 + i) * 2048 + dg * 8];

  for (int kt = 0; kt < nkt; ++kt) {
    const int t0 = kt * 128;
    __syncthreads();                       // B1: prior sP/sVt/sK reads done
    // ---- stage K rows -> sK (b128) ; V^T -> sVt via v_perm repack (b64) ----
    #pragma unroll
    for (int i = 0; i < 4; ++i)
      *(short8*)&sK[(rg * 4 + i) * SKS + dg * 8] = kv[i];
    {
      intx4 k0 = __builtin_bit_cast(intx4, kv[0]);
      intx4 k1 = __builtin_bit_cast(intx4, kv[1]);
      intx4 k2 = __builtin_bit_cast(intx4, kv[2]);
      intx4 k3 = __builtin_bit_cast(intx4, kv[3]);
      #pragma unroll
      for (int jj = 0; jj < 4; ++jj) {
        unsigned lo = __builtin_amdgcn_perm((unsigned)k1[jj], (unsigned)k0[jj], 0x05040100u);
        unsigned hi = __builtin_amdgcn_perm((unsigned)k3[jj], (unsigned)k2[jj], 0x05040100u);
        int j = 2 * jj, d = dg * 8 + j;
        int gsw = (swz0 + j) & 15;
        *(unsigned long long*)&sVt[d * SVS + gsw * 8 + (rg & 1) * 4] =
            (unsigned long long)lo | ((unsigned long long)hi << 32);
        lo = __builtin_amdgcn_perm((unsigned)k1[jj], (unsigned)k0[jj], 0x07060302u);
        hi = __builtin_amdgcn_perm((unsigned)k3[jj], (unsigned)k2[jj], 0x07060302u);
        j = 2 * jj + 1; d = dg * 8 + j;
        gsw = (swz0 + j) & 15;
        *(unsigned long long*)&sVt[d * SVS + gsw * 8 + (rg & 1) * 4] =
            (unsigned long long)lo | ((unsigned long long)hi << 32);
      }
    }
    __syncthreads();                       // B2: staging visible
    // ---- prefetch tile kt+1 (consumed after next B1; latency hidden) ----
    if (kt + 1 < nkt) {
      const long nb = base + (long)((kt + 1) * 128) * 2048;
      #pragma unroll
      for (int i = 0; i < 4; ++i)
        kv[i] = *(const short8*)&qkv[nb + (long)(rg * 4 + i) * 2048 + dg * 8];
    }
    // ---- Sc = Q K^T : wave w owns key-cols [w*32, w*32+32) ----
    floatx4 sacc[4][2];
    #pragma unroll
    for (int i = 0; i < 4; i++) { sacc[i][0] = z4; sacc[i][1] = z4; }
    #pragma unroll
    for (int ks = 0; ks < 2; ++ks) {
      short8 kf[2];
      #pragma unroll
      for (int nr = 0; nr < 2; nr++)
        kf[nr] = *(const short8*)&sK[(w * 32 + nr * 16 + l15) * SKS + ks * 32 + quad * 8];
      #pragma unroll
      for (int mr = 0; mr < 4; mr++)
        #pragma unroll
        for (int nr = 0; nr < 2; nr++)
          sacc[mr][nr] = __builtin_amdgcn_mfma_f32_16x16x32_bf16(qf[mr][ks], kf[nr], sacc[mr][nr], 0, 0, 0);
    }
    // ---- scale, silu, causal mask (last tile only) ----
    const bool diag = (kt == nkt - 1);
    #pragma unroll
    for (int mr = 0; mr < 4; mr++) {
      int row0 = mr * 16 + quad * 4;
      #pragma unroll
      for (int nr = 0; nr < 2; nr++) {
        int col = w * 32 + nr * 16 + l15;
        #pragma unroll
        for (int r = 0; r < 4; r++) {
          float v = silu_f(sacc[mr][nr][r] * 0.125f);
          if (diag && (q0 + row0 + r < t0 + col)) v = 0.f;
          sacc[mr][nr][r] = v;
        }
      }
    }
    __syncthreads();                       // B3: sK reads done (sP overlaps sK)
    #pragma unroll
    for (int mr = 0; mr < 4; mr++)
      #pragma unroll
      for (int nr = 0; nr < 2; nr++)
        #pragma unroll
        for (int r = 0; r < 4; r++)
          sP[(mr * 16 + quad * 4 + r) * SPS + w * 32 + nr * 16 + l15] = f2b(sacc[mr][nr][r]);
    __syncthreads();                       // B4: P visible
    // ---- O += P V : wave w owns d-cols [w*16, w*16+16) ----
    #pragma unroll
    for (int ts = 0; ts < 4; ++ts) {
      int gsw = (ts * 4 + rsw0) & 15;
      short8 vfr = *(const short8*)&sVt[d_rd * SVS + gsw * 8];
      #pragma unroll
      for (int mr = 0; mr < 4; mr++) {
        short8 pf = *(const short8*)&sP[(mr * 16 + l15) * SPS + ts * 32 + quad * 8];
        oacc[mr] = __builtin_amdgcn_mfma_f32_16x16x32_bf16(pf, vfr, oacc[mr], 0, 0, 0);
      }
    }
  }

  // ---- epilogue: O -> sO (f32), then coalesced full-line gated = O*u ----
  __syncthreads();                         // E1: all PV reads of sP/sVt done
  #pragma unroll
  for (int mr = 0; mr < 4; mr++)
    #pragma unroll
    for (int r = 0; r < 4; r++)
      sO[(mr * 16 + quad * 4 + r) * SOS + w * 16 + l15] = oacc[mr][r];
  __syncthreads();                         // E2: sO visible
  {
    const int erow = t >> 2, edg = t & 3;  // row 0..63, 16-d group 0..3
    const float* sOr = sO + erow * SOS + edg * 16;
    const long grow = (long)(q0 + erow) * 2048 + base + edg * 16;
    short8 u0 = *(const short8*)&u[grow];
    short8 u1 = *(const short8*)&u[grow + 8];
    short8 g0, g1;
    #pragma unroll
    for (int j = 0; j < 8; ++j) {
      g0[j] = (short)f2b(sOr[j]     * b2f((unsigned short)u0[j]));
      g1[j] = (short)f2b(sOr[j + 8] * b2f((unsigned short)u1[j]));
    }
    *(short8*)&gated[grow]     = g0;
    *(short8*)&gated[grow + 8] = g1;
  }
}

// ---------------------------------------------------------------- launch
extern "C" void kernel_launch(void* const* d_in, const int* in_sizes, int n_in,
                              void* d_out, int out_size, void* d_ws, size_t ws_size,
                              hipStream_t stream) {
  const float* src = (const float*)d_in[0];
  // d_in[1] = src_mask: tril, causality handled structurally
  const float* w1  = (const float*)d_in[2];
  const float* b1  = (const float*)d_in[3];
  const float* w2  = (const float*)d_in[4];
  const float* b2  = (const float*)d_in[5];
  const float* lng = (const float*)d_in[6];
  const float* lnb = (const float*)d_in[7];
  float* out = (float*)d_out;

  char* ws = (char*)d_ws;
  unsigned short* xn    = (unsigned short*)(ws + 0);          // 4096x1024 bf16
  unsigned short* qkv   = (unsigned short*)(ws + 8388608);    // 4096x1024 bf16
  unsigned short* uu    = (unsigned short*)(ws + 16777216);   // 4096x1024 bf16
  unsigned short* gated = (unsigned short*)(ws + 25165824);   // 4096x1024 bf16
  unsigned short* w1b   = (unsigned short*)(ws + 33554432);   // 2048x1024 bf16
  unsigned short* w2b   = (unsigned short*)(ws + 37748736);   // 1024x1024 bf16

  cvt_bf16<<<2048, 256, 0, stream>>>(w1, w1b, 524288);
  cvt_bf16<<<1024, 256, 0, stream>>>(w2, w2b, 262144);
  ln_kernel<<<4096, 256, 0, stream>>>(src, lng, lnb, xn);
  gemm_in<<<dim3(16, 32), 256, 0, stream>>>(xn, w1b, b1, qkv, uu);
  attn_kernel<<<1024, 256, 0, stream>>>(qkv, uu, gated);
  gemm_out<<<dim3(16, 32), 256, 0, stream>>>(gated, w2b, b2, src, out);
}

// Round 5
// 190.659 us; speedup vs baseline: 1.0389x; 1.0389x over previous
//
#include <hip/hip_runtime.h>

// ---------------------------------------------------------------------------
// HSTU encoder layer, MI355X.  S=2048 B=2 E=1024 H=16 D=64, M = S*B = 4096.
// cvt(W->bf16) -> LN -> GEMM(in_proj,silu) -> attn(QK^T,silu-mask,PV,*u)
//   -> GEMM 128x64 (out_proj,+src)
// All matmuls: v_mfma_f32_16x16x32_bf16, f32 accum.
// ---------------------------------------------------------------------------

typedef __attribute__((ext_vector_type(8))) short  short8;   // 8 bf16 = 4 VGPR
typedef __attribute__((ext_vector_type(4))) float  floatx4;  // MFMA C/D frag
typedef __attribute__((ext_vector_type(4))) float  fvec4;
typedef __attribute__((ext_vector_type(4))) unsigned short usvec4;
typedef __attribute__((ext_vector_type(4))) int    intx4;

__device__ __forceinline__ unsigned short f2b(float f) {  // f32 -> bf16 RNE
  unsigned u = __builtin_bit_cast(unsigned, f);
  u += 0x7FFFu + ((u >> 16) & 1u);
  return (unsigned short)(u >> 16);
}
__device__ __forceinline__ unsigned short f2b_trunc(float f) {  // 1-op truncate
  return (unsigned short)(__builtin_bit_cast(unsigned, f) >> 16);
}
__device__ __forceinline__ float b2f(unsigned short h) {
  unsigned u = ((unsigned)h) << 16;
  return __builtin_bit_cast(float, u);
}
// silu via raw v_exp/v_rcp: x<<0 -> exp2(+inf)->rcp->0 OK; x>>0 -> 1*x OK.
__device__ __forceinline__ float silu_f(float x) {
  float e = __builtin_amdgcn_exp2f(-1.44269504f * x);
  return x * __builtin_amdgcn_rcpf(1.f + e);
}
__device__ __forceinline__ void async_copy16(void* lds, const void* g) {
  __builtin_amdgcn_global_load_lds(
      (__attribute__((address_space(1))) void*)(g),
      (__attribute__((address_space(3))) void*)(lds), 16, 0, 0);
}

// ---------------------------------------------------------------- cvt f32->bf16 (both weights)
__global__ void cvt_bf16(const float* __restrict__ s1, unsigned short* __restrict__ d1,
                         const float* __restrict__ s2, unsigned short* __restrict__ d2,
                         int n1, int ntot) {
  int i = blockIdx.x * 256 + threadIdx.x;
  if (i >= ntot) return;
  const float* s; unsigned short* d; int j;
  if (i < n1) { s = s1; d = d1; j = i; } else { s = s2; d = d2; j = i - n1; }
  fvec4 v = ((const fvec4*)s)[j];
  usvec4 o = { f2b(v.x), f2b(v.y), f2b(v.z), f2b(v.w) };
  ((usvec4*)d)[j] = o;
}

// ---------------------------------------------------------------- LayerNorm
// One wave per row; pure shfl_xor reduction, no LDS/barriers. grid 1024 x 256.
__global__ __launch_bounds__(256) void ln_kernel(
    const float* __restrict__ x, const float* __restrict__ g,
    const float* __restrict__ b, unsigned short* __restrict__ xn) {
  const int lane = threadIdx.x & 63;
  const int row = blockIdx.x * 4 + (threadIdx.x >> 6);
  const fvec4* xr = (const fvec4*)(x + (long)row * 1024);
  fvec4 v[4];
  float s = 0.f, s2 = 0.f;
  #pragma unroll
  for (int c = 0; c < 4; ++c) {
    v[c] = xr[lane + 64 * c];
    s  += v[c].x + v[c].y + v[c].z + v[c].w;
    s2 += v[c].x*v[c].x + v[c].y*v[c].y + v[c].z*v[c].z + v[c].w*v[c].w;
  }
  #pragma unroll
  for (int off = 32; off; off >>= 1) { s += __shfl_xor(s, off); s2 += __shfl_xor(s2, off); }
  float mu  = s * (1.f / 1024.f);
  float var = s2 * (1.f / 1024.f) - mu * mu;
  float rs  = rsqrtf(var + 1e-5f);
  usvec4* outr = (usvec4*)(xn + (long)row * 1024);
  #pragma unroll
  for (int c = 0; c < 4; ++c) {
    fvec4 gg = ((const fvec4*)g)[lane + 64 * c];
    fvec4 bb = ((const fvec4*)b)[lane + 64 * c];
    usvec4 o = { f2b((v[c].x - mu) * rs * gg.x + bb.x),
                 f2b((v[c].y - mu) * rs * gg.y + bb.y),
                 f2b((v[c].z - mu) * rs * gg.z + bb.z),
                 f2b((v[c].w - mu) * rs * gg.w + bb.w) };
    outr[lane + 64 * c] = o;
  }
}

// ---------------------------------------------------------------- GEMM in_proj
// C = A * Bw^T, 128x128 tile.  A:(4096,1024) Bw:(2048,1024) bf16.
// epilogue: v=silu(v+bias); n<1024 -> qkv else u (both [m][1024] bf16)
__global__ __launch_bounds__(256, 2) void gemm_in(
    const unsigned short* __restrict__ A, const unsigned short* __restrict__ Bw,
    const float* __restrict__ bias,
    unsigned short* __restrict__ out0, unsigned short* __restrict__ out1) {
  __shared__ __align__(16) unsigned short sA[128 * 32];
  __shared__ __align__(16) unsigned short sB[128 * 32];
  const int t = threadIdx.x;
  const int lane = t & 63, l15 = lane & 15, quad = lane >> 4;
  const int w = t >> 6, wm = w >> 1, wn = w & 1;
  const int m0 = blockIdx.y * 128, n0 = blockIdx.x * 128;
  const int K = 1024;

  floatx4 acc[4][4];
  const floatx4 z4 = {0.f, 0.f, 0.f, 0.f};
  #pragma unroll
  for (int i = 0; i < 4; i++)
    #pragma unroll
    for (int j = 0; j < 4; j++) acc[i][j] = z4;

  for (int kt = 0; kt < 32; ++kt) {
    const int k0 = kt << 5;
    __syncthreads();
    #pragma unroll
    for (int c = 0; c < 2; ++c) {
      int slot = c * 256 + t;
      int row = slot >> 2, col = (slot & 3) << 3;
      async_copy16(&sA[slot * 8], &A[(m0 + row) * K + k0 + col]);
      async_copy16(&sB[slot * 8], &Bw[(n0 + row) * K + k0 + col]);
    }
    __syncthreads();
    short8 af[4], bf[4];
    #pragma unroll
    for (int mr = 0; mr < 4; mr++)
      af[mr] = *(const short8*)&sA[(wm * 64 + mr * 16 + l15) * 32 + quad * 8];
    #pragma unroll
    for (int nr = 0; nr < 4; nr++)
      bf[nr] = *(const short8*)&sB[(wn * 64 + nr * 16 + l15) * 32 + quad * 8];
    #pragma unroll
    for (int mr = 0; mr < 4; mr++)
      #pragma unroll
      for (int nr = 0; nr < 4; nr++)
        acc[mr][nr] = __builtin_amdgcn_mfma_f32_16x16x32_bf16(af[mr], bf[nr], acc[mr][nr], 0, 0, 0);
  }

  #pragma unroll
  for (int mr = 0; mr < 4; mr++) {
    int gm0 = m0 + wm * 64 + mr * 16 + quad * 4;
    #pragma unroll
    for (int nr = 0; nr < 4; nr++) {
      int gn = n0 + wn * 64 + nr * 16 + l15;
      float bv = bias[gn];
      unsigned short* dst = (gn < 1024) ? (out0 + gn) : (out1 + gn - 1024);
      #pragma unroll
      for (int r = 0; r < 4; r++) {
        float v = acc[mr][nr][r] + bv;
        dst[(long)(gm0 + r) * 1024] = f2b(silu_f(v));
      }
    }
  }
}

// ---------------------------------------------------------------- GEMM out_proj
// 128x64 tile (grid 512 -> 2 blocks/CU).
// outf[m][n] = acc + bias[n] + src[m][n]  (f32), N=K=1024.
__global__ __launch_bounds__(256, 2) void gemm_out(
    const unsigned short* __restrict__ A, const unsigned short* __restrict__ Bw,
    const float* __restrict__ bias, const float* __restrict__ src,
    float* __restrict__ outf) {
  __shared__ __align__(16) unsigned short sA[128 * 32];
  __shared__ __align__(16) unsigned short sB[64 * 32];
  const int t = threadIdx.x;
  const int lane = t & 63, l15 = lane & 15, quad = lane >> 4;
  const int w = t >> 6;
  const int m0 = blockIdx.y * 128, n0 = blockIdx.x * 64;

  floatx4 acc[2][4];
  const floatx4 z4 = {0.f, 0.f, 0.f, 0.f};
  #pragma unroll
  for (int i = 0; i < 2; i++)
    #pragma unroll
    for (int j = 0; j < 4; j++) acc[i][j] = z4;

  for (int kt = 0; kt < 32; ++kt) {
    const int k0 = kt << 5;
    __syncthreads();
    #pragma unroll
    for (int c = 0; c < 2; ++c) {
      int slot = c * 256 + t;
      int row = slot >> 2, col = (slot & 3) << 3;
      async_copy16(&sA[slot * 8], &A[(m0 + row) * 1024 + k0 + col]);
    }
    { int row = t >> 2, col = (t & 3) << 3;
      async_copy16(&sB[t * 8], &Bw[(n0 + row) * 1024 + k0 + col]); }
    __syncthreads();
    short8 af[2], bf[4];
    #pragma unroll
    for (int mr = 0; mr < 2; mr++)
      af[mr] = *(const short8*)&sA[(w * 32 + mr * 16 + l15) * 32 + quad * 8];
    #pragma unroll
    for (int nr = 0; nr < 4; nr++)
      bf[nr] = *(const short8*)&sB[(nr * 16 + l15) * 32 + quad * 8];
    #pragma unroll
    for (int mr = 0; mr < 2; mr++)
      #pragma unroll
      for (int nr = 0; nr < 4; nr++)
        acc[mr][nr] = __builtin_amdgcn_mfma_f32_16x16x32_bf16(af[mr], bf[nr], acc[mr][nr], 0, 0, 0);
  }

  #pragma unroll
  for (int mr = 0; mr < 2; mr++) {
    int gm0 = m0 + w * 32 + mr * 16 + quad * 4;
    #pragma unroll
    for (int nr = 0; nr < 4; nr++) {
      int gn = n0 + nr * 16 + l15;
      float bv = bias[gn];
      #pragma unroll
      for (int r = 0; r < 4; r++) {
        long idx = (long)(gm0 + r) * 1024 + gn;
        outf[idx] = acc[mr][nr][r] + bv + src[idx];
      }
    }
  }
}

// ---------------------------------------------------------------- attention
// grid 512: block = (pair 0..15, bh 0..31); processes q-tiles {pair, 31-pair}
// sequentially -> every block runs exactly 17 k-iterations (uniform, no tail).
// Per q-tile: stage Q -> loop k-tiles {stage K+V^T, QK^T, silu/mask, sP, PV}
//   -> epilogue gated = O*u via sO (coalesced full-line stores).
#define SKS 72    // sK row stride (ushorts) - conflict-free reads/writes
#define SVS 136   // sVt row stride
#define SPS 136   // sP  row stride
#define SOS 68    // sO  row stride (f32)
__global__ __launch_bounds__(256, 2) void attn_kernel(
    const unsigned short* __restrict__ qkv, const unsigned short* __restrict__ u,
    unsigned short* __restrict__ gated) {
  __shared__ __align__(16) unsigned char smem[128 * SKS * 2 + 64 * SVS * 2];  // 35840 B
  unsigned short* sK  = (unsigned short*)smem;                   // [128][72]
  unsigned short* sP  = (unsigned short*)smem;                   // [64][136] (overlaps sK)
  unsigned short* sVt = (unsigned short*)(smem + 128 * SKS * 2); // [64][136] swizzled
  float*          sO  = (float*)smem;                            // [64][68] f32 (epilogue)

  const int t = threadIdx.x, lane = t & 63, l15 = lane & 15, quad = lane >> 4;
  const int w = t >> 6;
  const int pair = blockIdx.x >> 5;
  const int bh = blockIdx.x & 31;
  const int b = bh >> 4, h = bh & 15;
  const long base = (long)b * 1024 + h * 64;   // + s*2048
  const int rg = t >> 3, dg = t & 7;           // staging: rows rg*4..+4, cols dg*8..+8
  const int swz0 = (rg >> 1) + dg;             // sVt write-side swizzle base
  const int d_rd = w * 16 + l15;               // PV read: this lane's d column
  const int rsw0 = quad + (d_rd & 7) + (d_rd >> 3);  // sVt read-side swizzle base
  const floatx4 z4 = {0.f, 0.f, 0.f, 0.f};

  for (int half = 0; half < 2; ++half) {
    const int qi = half ? (31 - pair) : pair;
    const int q0 = qi * 64;
    const int nkt = (qi >> 1) + 1;

    if (half) __syncthreads();           // E3: prior epilogue sO reads done
    // ---- stage Q (64 rows) via sK, pull A-frags to registers ----
    #pragma unroll
    for (int c = 0; c < 2; ++c) {
      int slot = c * 256 + t, row = slot >> 3, cg = slot & 7;
      *(short8*)&sK[row * SKS + cg * 8] =
          *(const short8*)&qkv[base + (long)(q0 + row) * 2048 + cg * 8];
    }
    __syncthreads();
    short8 qf[4][2];
    #pragma unroll
    for (int mr = 0; mr < 4; mr++)
      #pragma unroll
      for (int ks = 0; ks < 2; ks++)
        qf[mr][ks] = *(const short8*)&sK[(mr * 16 + l15) * SKS + ks * 32 + quad * 8];

    floatx4 oacc[4];
    #pragma unroll
    for (int i = 0; i < 4; i++) oacc[i] = z4;

    for (int kt = 0; kt < nkt; ++kt) {
      const int t0 = kt * 128;
      __syncthreads();                   // B1: prior sP/sVt/sK reads done
      // ---- stage K rows -> sK (b128) ; V^T -> sVt via v_perm repack (b64) ----
      short8 kv[4];
      #pragma unroll
      for (int i = 0; i < 4; ++i)
        kv[i] = *(const short8*)&qkv[base + (long)(t0 + rg * 4 + i) * 2048 + dg * 8];
      #pragma unroll
      for (int i = 0; i < 4; ++i)
        *(short8*)&sK[(rg * 4 + i) * SKS + dg * 8] = kv[i];
      {
        intx4 k0 = __builtin_bit_cast(intx4, kv[0]);
        intx4 k1 = __builtin_bit_cast(intx4, kv[1]);
        intx4 k2 = __builtin_bit_cast(intx4, kv[2]);
        intx4 k3 = __builtin_bit_cast(intx4, kv[3]);
        #pragma unroll
        for (int jj = 0; jj < 4; ++jj) {
          unsigned lo = __builtin_amdgcn_perm((unsigned)k1[jj], (unsigned)k0[jj], 0x05040100u);
          unsigned hi = __builtin_amdgcn_perm((unsigned)k3[jj], (unsigned)k2[jj], 0x05040100u);
          int j = 2 * jj, d = dg * 8 + j;
          int gsw = (swz0 + j) & 15;
          *(unsigned long long*)&sVt[d * SVS + gsw * 8 + (rg & 1) * 4] =
              (unsigned long long)lo | ((unsigned long long)hi << 32);
          lo = __builtin_amdgcn_perm((unsigned)k1[jj], (unsigned)k0[jj], 0x07060302u);
          hi = __builtin_amdgcn_perm((unsigned)k3[jj], (unsigned)k2[jj], 0x07060302u);
          j = 2 * jj + 1; d = dg * 8 + j;
          gsw = (swz0 + j) & 15;
          *(unsigned long long*)&sVt[d * SVS + gsw * 8 + (rg & 1) * 4] =
              (unsigned long long)lo | ((unsigned long long)hi << 32);
        }
      }
      __syncthreads();                   // B2: staging visible
      // ---- Sc = Q K^T : wave w owns key-cols [w*32, w*32+32) ----
      floatx4 sacc[4][2];
      #pragma unroll
      for (int i = 0; i < 4; i++) { sacc[i][0] = z4; sacc[i][1] = z4; }
      #pragma unroll
      for (int ks = 0; ks < 2; ++ks) {
        short8 kf[2];
        #pragma unroll
        for (int nr = 0; nr < 2; nr++)
          kf[nr] = *(const short8*)&sK[(w * 32 + nr * 16 + l15) * SKS + ks * 32 + quad * 8];
        #pragma unroll
        for (int mr = 0; mr < 4; mr++)
          #pragma unroll
          for (int nr = 0; nr < 2; nr++)
            sacc[mr][nr] = __builtin_amdgcn_mfma_f32_16x16x32_bf16(qf[mr][ks], kf[nr], sacc[mr][nr], 0, 0, 0);
      }
      // ---- scale, silu, causal mask (last tile only) ----
      const bool diag = (kt == nkt - 1);
      #pragma unroll
      for (int mr = 0; mr < 4; mr++) {
        int row0 = mr * 16 + quad * 4;
        #pragma unroll
        for (int nr = 0; nr < 2; nr++) {
          int col = w * 32 + nr * 16 + l15;
          #pragma unroll
          for (int r = 0; r < 4; r++) {
            float v = silu_f(sacc[mr][nr][r] * 0.125f);
            if (diag && (q0 + row0 + r < t0 + col)) v = 0.f;
            sacc[mr][nr][r] = v;
          }
        }
      }
      __syncthreads();                   // B3: sK reads done (sP overlaps sK)
      #pragma unroll
      for (int mr = 0; mr < 4; mr++)
        #pragma unroll
        for (int nr = 0; nr < 2; nr++)
          #pragma unroll
          for (int r = 0; r < 4; r++)
            sP[(mr * 16 + quad * 4 + r) * SPS + w * 32 + nr * 16 + l15] =
                f2b_trunc(sacc[mr][nr][r]);
      __syncthreads();                   // B4: P visible
      // ---- O += P V : wave w owns d-cols [w*16, w*16+16) ----
      #pragma unroll
      for (int ts = 0; ts < 4; ++ts) {
        int gsw = (ts * 4 + rsw0) & 15;
        short8 vfr = *(const short8*)&sVt[d_rd * SVS + gsw * 8];
        #pragma unroll
        for (int mr = 0; mr < 4; mr++) {
          short8 pf = *(const short8*)&sP[(mr * 16 + l15) * SPS + ts * 32 + quad * 8];
          oacc[mr] = __builtin_amdgcn_mfma_f32_16x16x32_bf16(pf, vfr, oacc[mr], 0, 0, 0);
        }
      }
    }

    // ---- epilogue: O -> sO (f32), then coalesced full-line gated = O*u ----
    __syncthreads();                     // E1: all PV reads of sP/sVt done
    #pragma unroll
    for (int mr = 0; mr < 4; mr++)
      #pragma unroll
      for (int r = 0; r < 4; r++)
        sO[(mr * 16 + quad * 4 + r) * SOS + w * 16 + l15] = oacc[mr][r];
    __syncthreads();                     // E2: sO visible
    {
      const int erow = t >> 2, edg = t & 3;  // row 0..63, 16-d group 0..3
      const float* sOr = sO + erow * SOS + edg * 16;
      const long grow = (long)(q0 + erow) * 2048 + base + edg * 16;
      short8 u0 = *(const short8*)&u[grow];
      short8 u1 = *(const short8*)&u[grow + 8];
      short8 g0, g1;
      #pragma unroll
      for (int j = 0; j < 8; ++j) {
        g0[j] = (short)f2b(sOr[j]     * b2f((unsigned short)u0[j]));
        g1[j] = (short)f2b(sOr[j + 8] * b2f((unsigned short)u1[j]));
      }
      *(short8*)&gated[grow]     = g0;
      *(short8*)&gated[grow + 8] = g1;
    }
  }
}

// ---------------------------------------------------------------- launch
extern "C" void kernel_launch(void* const* d_in, const int* in_sizes, int n_in,
                              void* d_out, int out_size, void* d_ws, size_t ws_size,
                              hipStream_t stream) {
  const float* src = (const float*)d_in[0];
  // d_in[1] = src_mask: tril, causality handled structurally
  const float* w1  = (const float*)d_in[2];
  const float* b1  = (const float*)d_in[3];
  const float* w2  = (const float*)d_in[4];
  const float* b2  = (const float*)d_in[5];
  const float* lng = (const float*)d_in[6];
  const float* lnb = (const float*)d_in[7];
  float* out = (float*)d_out;

  char* ws = (char*)d_ws;
  unsigned short* xn    = (unsigned short*)(ws + 0);          // 4096x1024 bf16
  unsigned short* qkv   = (unsigned short*)(ws + 8388608);    // 4096x1024 bf16
  unsigned short* uu    = (unsigned short*)(ws + 16777216);   // 4096x1024 bf16
  unsigned short* gated = (unsigned short*)(ws + 25165824);   // 4096x1024 bf16
  unsigned short* w1b   = (unsigned short*)(ws + 33554432);   // 2048x1024 bf16
  unsigned short* w2b   = (unsigned short*)(ws + 37748736);   // 1024x1024 bf16

  cvt_bf16<<<3072, 256, 0, stream>>>(w1, w1b, w2, w2b, 524288, 786432);
  ln_kernel<<<1024, 256, 0, stream>>>(src, lng, lnb, xn);
  gemm_in<<<dim3(16, 32), 256, 0, stream>>>(xn, w1b, b1, qkv, uu);
  attn_kernel<<<512, 256, 0, stream>>>(qkv, uu, gated);
  gemm_out<<<dim3(16, 32), 256, 0, stream>>>(gated, w2b, b2, src, out);
}